// Round 5
// baseline (333.022 us; speedup 1.0000x reference)
//
#include <hip/hip_runtime.h>
#include <stdint.h>

// B=16, S=2048, D=128 attention, per-query scale folded into Q (with log2e),
// online softmax in exp2 domain, exact JAX partitionable-threefry dropout
// (key 42, p=0.1), @V.
// History: R10 259.6us (TQ=64, 4 waves, VALU 62.5%, Occ 19.4%); R11 261us
// (deferred-l+THR8: VALU work fell, dur flat -> stall-bound); R12 279us
// (8 thin waves: +25% VALU from duplicated staging/convert, Occ only 23%).
// Round 13 (this): delete the staging machinery to unlock occupancy.
//  - pre-pass 1: K -> f16 copy (workspace), same [b][key][d] layout.
//  - pre-pass 2: V -> f16 transposed V^T[b][kt][d:128][key:72pad] (VSTR=72,
//    the proven 2-way-bank-free stride).
//  - main: K frags global->reg (no K LDS, no converts; L1/L2 serve reuse);
//    V staged via global_load_lds (no VGPR round-trip, no convert VALU);
//    8 waves x 16 q-rows, LDS 47104 B, launch_bounds(512,4) targeting
//    4 waves/SIMD (16 waves/CU, 2 blocks/CU).

#define B_ 16
#define S_ 2048
#define D_ 128
#define TQ 64     // q rows per block (4 subtiles x 16)
#define TK 64     // keys per iteration (each kph-wave consumes 32)
#define NT (S_ / TK)
#define VSTR 72   // f16 stride for V^T rows (64+8): 144B, 2-way banks (free)
#define PSTR 40   // f16 stride for per-wave P rows (32+8): 80B
#define VTILE (D_ * VSTR)                 // 9216 f16 = 18432 B per (b,kt) tile
#define KST_ELEMS ((size_t)B_ * S_ * D_)  // 4194304 f16 = 8 MB

typedef float f32x4 __attribute__((ext_vector_type(4)));
typedef _Float16 f16x8 __attribute__((ext_vector_type(8)));
typedef _Float16 f16x4 __attribute__((ext_vector_type(4)));

// DPP row_ror reductions over 16-lane row groups.
#define DPP_ROR(x, ctrl) \
  __int_as_float(__builtin_amdgcn_update_dpp(0, __float_as_int(x), (ctrl), 0xf, 0xf, true))
__device__ __forceinline__ float row16_max(float x) {
  x = fmaxf(x, DPP_ROR(x, 0x128));
  x = fmaxf(x, DPP_ROR(x, 0x124));
  x = fmaxf(x, DPP_ROR(x, 0x122));
  x = fmaxf(x, DPP_ROR(x, 0x121));
  return x;
}
__device__ __forceinline__ float row16_sum(float x) {
  x += DPP_ROR(x, 0x128);
  x += DPP_ROR(x, 0x124);
  x += DPP_ROR(x, 0x122);
  x += DPP_ROR(x, 0x121);
  return x;
}

// threefry2x32, 20 rounds, key = (0, 42)  [jax.random.key(42)]
__device__ __forceinline__ uint2 threefry2x32_0_42(uint32_t x0, uint32_t x1) {
  const uint32_t k0 = 0u, k1 = 42u;
  const uint32_t k2 = 0x1BD11BDAu ^ k0 ^ k1;
  x0 += k0; x1 += k1;
#define TFR(r) { x0 += x1; x1 = __builtin_rotateleft32(x1, r); x1 ^= x0; }
  TFR(13) TFR(15) TFR(26) TFR(6)
  x0 += k1; x1 += k2 + 1u;
  TFR(17) TFR(29) TFR(16) TFR(24)
  x0 += k2; x1 += k0 + 2u;
  TFR(13) TFR(15) TFR(26) TFR(6)
  x0 += k0; x1 += k1 + 3u;
  TFR(17) TFR(29) TFR(16) TFR(24)
  x0 += k1; x1 += k2 + 4u;
  TFR(13) TFR(15) TFR(26) TFR(6)
  x0 += k2; x1 += k0 + 5u;
#undef TFR
  return make_uint2(x0, x1);
}

// HW-verified (prev session): partitionable path, counter (0, j), xor-fold.
__device__ __forceinline__ uint32_t jax_bits(uint32_t j) {
  const uint2 tf = threefry2x32_0_42(0u, j);
  return tf.x ^ tf.y;
}

// ---- pre-pass 1: K f32 -> f16, identical layout ----
__global__ __launch_bounds__(256)
void prep_k(const float* __restrict__ K, _Float16* __restrict__ Kst) {
  const size_t i = ((size_t)blockIdx.x * 256 + threadIdx.x) * 4;
  const float4 x = *(const float4*)(K + i);
  f16x4 h = {(_Float16)x.x, (_Float16)x.y, (_Float16)x.z, (_Float16)x.w};
  *(f16x4*)(Kst + i) = h;
}

// ---- pre-pass 2: V f32 -> f16 transposed, per (b,kt) tile [d:128][key:72pad] ----
__global__ __launch_bounds__(256)
void prep_v(const float* __restrict__ V, _Float16* __restrict__ Vst) {
  __shared__ _Float16 sT[64 * 132];   // [key][d] padded
  const int b = blockIdx.y, kt = blockIdx.x, t = threadIdx.x;
  const int key = t >> 2, dq = t & 3;
  const float* vp = V + ((size_t)(b * S_ + kt * 64 + key)) * D_ + dq * 32;
  #pragma unroll
  for (int i = 0; i < 8; ++i) {
    const float4 x = *(const float4*)(vp + i * 4);
    _Float16* d = &sT[key * 132 + dq * 32 + i * 4];
    d[0] = (_Float16)x.x; d[1] = (_Float16)x.y;
    d[2] = (_Float16)x.z; d[3] = (_Float16)x.w;
  }
  __syncthreads();
  _Float16* tile = Vst + (size_t)(b * NT + kt) * VTILE;
  #pragma unroll
  for (int it = 0; it < 4; ++it) {
    const int idx = t * 4 + it;          // 1024 items: (d:128, kg:8)
    const int d = idx >> 3, kg = idx & 7;
    f16x8 v;
    #pragma unroll
    for (int j = 0; j < 8; ++j) v[j] = sT[(kg * 8 + j) * 132 + d];
    *(f16x8*)&tile[d * VSTR + kg * 8] = v;
  }
}

__global__ __launch_bounds__(512, 4)
void attn_mfma_kernel(const float* __restrict__ Q, const _Float16* __restrict__ Kst,
                      const _Float16* __restrict__ Vst, const float* __restrict__ ISF,
                      const float* __restrict__ DP, float* __restrict__ OUT) {
  __shared__ __align__(16) char smem[47104];
  char* const sVT0 = smem;                              // 128x72 f16 = 18432 B
  char* const sVT1 = smem + 18432;
  _Float16* const sP = (_Float16*)(smem + 36864);       // 8 x 16x40 f16 = 10240 B
  // merge overlay (after final barrier):
  float* const sO1 = (float*)smem;                      // 64x128 f32 = 32768 B
  float* const sM1 = (float*)(smem + 32768);            // 64 f32
  float* const sL1 = (float*)(smem + 33024);            // 64 f32

  const int t    = threadIdx.x;
  const int lane = t & 63;
  const int l15  = lane & 15;
  const int quad = lane >> 4;
  const int w    = t >> 6;       // 0..7
  const int qsub = w >> 1;       // q-subtile (16 rows), 0..3
  const int kph  = w & 1;        // key phase: 0 = keys [0,32), 1 = [32,64)
  const int b    = blockIdx.y;
  const int qb   = blockIdx.x * TQ + qsub * 16;

  const float kp = 1.0f - DP[0];
  const uint32_t TH9 = (__float_as_uint(1.0f + kp) & 0x7FFFFFu) << 9;

  float m_[4], l_[4];
  uint32_t jq[4];
  #pragma unroll
  for (int r = 0; r < 4; ++r) {
    m_[r] = -INFINITY;
    l_[r] = 0.0f;
    jq[r] = ((uint32_t)b << 22)
          + (uint32_t)(qb + quad * 4 + r) * (uint32_t)S_;
  }

  // ---- Q fragment (1 subtile), f16, 1/isf and log2(e) folded in ----
  f16x8 qf[4];
  {
    const int qrow = qb + l15;
    const float qs = 1.4426950408889634f / ISF[b * S_ + qrow];
    const float* qp = Q + ((size_t)(b * S_ + qrow)) * D_;
    #pragma unroll
    for (int c = 0; c < 4; ++c) {
      const float4 a  = *(const float4*)(qp + c * 32 + quad * 8);
      const float4 d2 = *(const float4*)(qp + c * 32 + quad * 8 + 4);
      const float xs[8] = {a.x, a.y, a.z, a.w, d2.x, d2.y, d2.z, d2.w};
      f16x8 h;
      #pragma unroll
      for (int j = 0; j < 8; ++j) h[j] = (_Float16)(xs[j] * qs);
      qf[c] = h;
    }
  }

  f32x4 accO[8];
  #pragma unroll
  for (int i = 0; i < 8; ++i) accO[i] = (f32x4){0.f, 0.f, 0.f, 0.f};

  _Float16* const pwv = &sP[w * 16 * PSTR];

// stage V^T tile VT into buffer SV (18 x 1024B segments, wave-striped)
#define STAGE_V(VT, SV)                                                        \
  {                                                                            \
    const char* vsrc = (const char*)(Vst + (size_t)(b * NT + (VT)) * VTILE);   \
    for (int s8 = w; s8 < 18; s8 += 8) {                                       \
      __builtin_amdgcn_global_load_lds(                                        \
          (const unsigned int*)(vsrc + s8 * 1024 + lane * 16),                 \
          (unsigned int*)((SV) + s8 * 1024), 16, 0, 0);                        \
    }                                                                          \
  }

  // ---- prologue: stage tile 0 ----
  STAGE_V(0, sVT0)
  __syncthreads();

  for (int kt = 0; kt < NT; ++kt) {
    const int cur = kt & 1;
    char* const sVc = cur ? sVT1 : sVT0;

    // ---- QK^T: K frags straight from global f16 (L1/L2-resident) ----
    const _Float16* kb = Kst + ((size_t)(b * S_ + kt * TK + kph * 32)) * D_;
    f16x8 kf[2][4];
    #pragma unroll
    for (int n = 0; n < 2; ++n)
      #pragma unroll
      for (int c = 0; c < 4; ++c)
        kf[n][c] = *(const f16x8*)(kb + (n * 16 + l15) * D_ + c * 32 + quad * 8);

    f32x4 s[2];
    #pragma unroll
    for (int n = 0; n < 2; ++n) {
      f32x4 a0 = (f32x4){0.f, 0.f, 0.f, 0.f};
      #pragma unroll
      for (int c = 0; c < 4; ++c)
        a0 = __builtin_amdgcn_mfma_f32_16x16x32_f16(qf[c], kf[n][c], a0, 0, 0, 0);
      s[n] = a0;
    }

    // ---- stage V for kt+1 into the other buffer (async, drains at barrier) ----
    if (kt + 1 < NT) {
      char* const sVn = cur ? sVT0 : sVT1;
      STAGE_V(kt + 1, sVn)
    }

    // ---- dropout bits (independent of scores) ----
    uint32_t rb[2][4];
    #pragma unroll
    for (int n = 0; n < 2; ++n) {
      const uint32_t jcol = (uint32_t)(kt * TK + kph * 32 + n * 16 + l15);
      #pragma unroll
      for (int r = 0; r < 4; ++r)
        rb[n][r] = jax_bits(jq[r] + jcol);
    }

    // ---- online softmax (exp2 domain), threshold-deferred rescale ----
    float mx[4];
    int changed = 0;
    #pragma unroll
    for (int r = 0; r < 4; ++r) {
      mx[r] = row16_max(fmaxf(s[0][r], s[1][r]));
      changed |= (mx[r] > m_[r] + 8.0f);   // T13: defer small growth
    }
    if (__ballot(changed) != 0ull) {
      #pragma unroll
      for (int r = 0; r < 4; ++r) {
        const float mnew = fmaxf(m_[r], mx[r]);
        const float alpha = __builtin_amdgcn_exp2f(m_[r] - mnew);
        m_[r] = mnew;
        l_[r] *= alpha;
        #pragma unroll
        for (int i = 0; i < 8; ++i) accO[i][r] *= alpha;
      }
    }
    // p bounded by 2^8=256 (THR); l_ is a per-lane partial, reduced post-loop.
    #pragma unroll
    for (int r = 0; r < 4; ++r) {
      const float p0 = __builtin_amdgcn_exp2f(s[0][r] - m_[r]);
      const float p1 = __builtin_amdgcn_exp2f(s[1][r] - m_[r]);
      s[0][r] = p0;
      s[1][r] = p1;
      l_[r] += p0 + p1;
    }

    // ---- masked f16 P into wave-private LDS ----
    #pragma unroll
    for (int n = 0; n < 2; ++n) {
      const int col = n * 16 + l15;
      #pragma unroll
      for (int r = 0; r < 4; ++r) {
        const float pf = (rb[n][r] < TH9) ? s[n][r] : 0.0f;
        pwv[(quad * 4 + r) * PSTR + col] = (_Float16)pf;
      }
    }
    __threadfence_block();   // order cross-lane P writes before A-frag reads

    // ---- PV: O[16x128] += P[16x32] * V[32x128] ----
    {
      const f16x8 ap = *(const f16x8*)&pwv[l15 * PSTR + quad * 8];
      const _Float16* vb = (const _Float16*)sVc;
      #pragma unroll
      for (int d8 = 0; d8 < 8; ++d8) {
        const f16x8 bv = *(const f16x8*)&vb[(d8 * 16 + l15) * VSTR
                                            + kph * 32 + quad * 8];
        accO[d8] = __builtin_amdgcn_mfma_f32_16x16x32_f16(ap, bv, accO[d8], 0, 0, 0);
      }
    }

    __syncthreads();   // single barrier per iteration (also drains V stage)
  }
#undef STAGE_V

  // ---- deferred l row-reduction ----
  #pragma unroll
  for (int r = 0; r < 4; ++r)
    l_[r] = row16_sum(l_[r]);

  // ---- merge the two key-phase waves of each q-subtile ----
  if (kph == 1) {
    if (l15 == 0) {
      #pragma unroll
      for (int r = 0; r < 4; ++r) {
        const int gr = qsub * 16 + quad * 4 + r;
        sM1[gr] = m_[r];
        sL1[gr] = l_[r];
      }
    }
    #pragma unroll
    for (int d8 = 0; d8 < 8; ++d8)
      #pragma unroll
      for (int r = 0; r < 4; ++r) {
        const int gr = qsub * 16 + quad * 4 + r;
        sO1[gr * D_ + d8 * 16 + l15] = accO[d8][r];
      }
  }
  __syncthreads();
  if (kph == 0) {
    float a0s[4], a1s[4];
    #pragma unroll
    for (int r = 0; r < 4; ++r) {
      const int gr = qsub * 16 + quad * 4 + r;
      const float m1  = sM1[gr];
      const float l1v = sL1[gr];
      const float mf = fmaxf(m_[r], m1);
      const float a0 = __builtin_amdgcn_exp2f(m_[r] - mf);
      const float a1 = __builtin_amdgcn_exp2f(m1 - mf);
      const float inv = 1.0f / ((a0 * l_[r] + a1 * l1v) * kp);
      a0s[r] = a0 * inv;
      a1s[r] = a1 * inv;
    }
    #pragma unroll
    for (int d8 = 0; d8 < 8; ++d8)
      #pragma unroll
      for (int r = 0; r < 4; ++r) {
        const int gr = qsub * 16 + quad * 4 + r;
        const float o1 = sO1[gr * D_ + d8 * 16 + l15];
        OUT[((size_t)(b * S_ + blockIdx.x * TQ + gr)) * D_ + d8 * 16 + l15] =
            accO[d8][r] * a0s[r] + o1 * a1s[r];
      }
  }
}

extern "C" void kernel_launch(void* const* d_in, const int* in_sizes, int n_in,
                              void* d_out, int out_size, void* d_ws, size_t ws_size,
                              hipStream_t stream) {
  const float* q   = (const float*)d_in[0];
  const float* k   = (const float*)d_in[1];
  const float* v   = (const float*)d_in[2];
  const float* isf = (const float*)d_in[3];
  const float* dp  = (const float*)d_in[4];
  float* out = (float*)d_out;

  _Float16* kst = (_Float16*)d_ws;                 // 4194304 f16 = 8 MB
  _Float16* vst = kst + KST_ELEMS;                 // 4718592 f16 = 9 MB

  prep_k<<<dim3(4096), dim3(256), 0, stream>>>(k, kst);
  prep_v<<<dim3(NT, B_), dim3(256), 0, stream>>>(v, vst);

  dim3 grid(S_ / TQ, B_);
  attn_mfma_kernel<<<grid, dim3(512), 0, stream>>>(q, kst, vst, isf, dp, out);
}